// Round 11
// baseline (197.984 us; speedup 1.0000x reference)
//
#include <hip/hip_runtime.h>
#include <hip/hip_bf16.h>
#include <math.h>

#define Hd 128
#define Tt 256
#define Bb 1024
#define CL 16           // time-chunk length
#define NCK (Tt / CL)   // 16 chunks

typedef __attribute__((ext_vector_type(8))) short short8;
typedef __attribute__((ext_vector_type(4))) float f32x4;

__device__ __forceinline__ short f2bf(float f) {
    unsigned u = __float_as_uint(f);
    u += 0x7fffu + ((u >> 16) & 1u);   // RNE
    return (short)(u >> 16);
}
__device__ __forceinline__ float bflo(unsigned u) { return __uint_as_float(u << 16); }
__device__ __forceinline__ float bfhi(unsigned u) { return __uint_as_float(u & 0xffff0000u); }

// Weights -> bf16 MFMA B-frag layout [nt][kf][lane][8].  (verbatim)
__global__ void prep_weights(const float* __restrict__ Wih,
                             const float* __restrict__ Whh,
                             const float* __restrict__ fcW,
                             short* __restrict__ oIh, short* __restrict__ oHh,
                             short* __restrict__ oFc) {
    int t = blockIdx.x * 256 + threadIdx.x;
    if (t >= 14336) return;
    const float* src;
    short* dst;
    if (t < 6144)       { src = Wih; dst = oIh + t * 8; }
    else if (t < 12288) { t -= 6144;  src = Whh; dst = oHh + t * 8; }
    else                { t -= 12288; src = fcW; dst = oFc + t * 8; }
    int lane = t & 63, kf = (t >> 6) & 3, nt = t >> 8;
    const float* s = src + (nt * 16 + (lane & 15)) * 128 + kf * 32 + 8 * (lane >> 4);
#pragma unroll
    for (int j = 0; j < 8; j++) dst[j] = f2bf(s[j]);
}

// K2: xi = x@W_ih^T (+bih, +bhh for r/z cols) in C-frag order.  (verbatim)
__global__ __launch_bounds__(512)
void xi_gemm(const float* __restrict__ x, const float* __restrict__ bih,
             const float* __restrict__ bhh, const short* __restrict__ wIh,
             short* __restrict__ xi_l) {
    __shared__ short xs[64 * 136];
    const int tid = threadIdx.x, wv = tid >> 6, ln = tid & 63;
    const int q = ln & 15, lg = ln >> 4;
    const int bg = blockIdx.x;
    const int sl0 = blockIdx.y * 4;
    {
        const int row = tid >> 3, kq = tid & 7;
        const int b = row & 15, dt = row >> 4;
        const float* xp = x + (((size_t)(bg * 16 + b)) * Tt + (sl0 + dt)) * Hd + kq * 16;
        f32x4 u0 = *(const f32x4*)&xp[0],  u1 = *(const f32x4*)&xp[4];
        f32x4 u2 = *(const f32x4*)&xp[8],  u3 = *(const f32x4*)&xp[12];
        short8 s0, s1;
#pragma unroll
        for (int i = 0; i < 4; i++) { s0[i] = f2bf(u0[i]); s0[i+4] = f2bf(u1[i]);
                                      s1[i] = f2bf(u2[i]); s1[i+4] = f2bf(u3[i]); }
        *(short8*)&xs[row * 136 + kq * 16] = s0;
        *(short8*)&xs[row * 136 + kq * 16 + 8] = s1;
    }
    __syncthreads();
    short8 wb[3][4];
#pragma unroll
    for (int i = 0; i < 3; i++)
#pragma unroll
        for (int kf = 0; kf < 4; kf++)
            wb[i][kf] = *(const short8*)&wIh[(((wv + 8 * i) * 4 + kf) * 64 + ln) * 8];
    float biasv[3];
#pragma unroll
    for (int i = 0; i < 3; i++) {
        int c = (wv + 8 * i) * 16 + q;
        biasv[i] = bih[c] + (c < 256 ? bhh[c] : 0.f);
    }
#pragma unroll 1
    for (int mt = 0; mt < 4; mt++) {
        short8 af[4];
#pragma unroll
        for (int kf = 0; kf < 4; kf++)
            af[kf] = *(const short8*)&xs[(mt * 16 + q) * 136 + kf * 32 + 8 * lg];
        f32x4 c0 = {0,0,0,0}, c1 = {0,0,0,0}, c2 = {0,0,0,0};
#pragma unroll
        for (int kf = 0; kf < 4; kf++) {
            c0 = __builtin_amdgcn_mfma_f32_16x16x32_bf16(af[kf], wb[0][kf], c0, 0, 0, 0);
            c1 = __builtin_amdgcn_mfma_f32_16x16x32_bf16(af[kf], wb[1][kf], c1, 0, 0, 0);
            c2 = __builtin_amdgcn_mfma_f32_16x16x32_bf16(af[kf], wb[2][kf], c2, 0, 0, 0);
        }
#pragma unroll
        for (int i = 0; i < 3; i++) {
            f32x4 cc = (i == 0) ? c0 : (i == 1) ? c1 : c2;
            unsigned d0 = (unsigned)(unsigned short)f2bf(cc[0] + biasv[i]) |
                          ((unsigned)(unsigned short)f2bf(cc[1] + biasv[i]) << 16);
            unsigned d1 = (unsigned)(unsigned short)f2bf(cc[2] + biasv[i]) |
                          ((unsigned)(unsigned short)f2bf(cc[3] + biasv[i]) << 16);
            uint2 dd = {d0, d1};
            ((uint2*)xi_l)[(((size_t)bg * Tt + (sl0 + mt)) * 24 + (wv + 8 * i)) * 64 + ln] = dd;
        }
    }
}

// K3: time-chunked recurrence, R11: 512 threads / 8 waves per block.
// Wave w owns gate cols 16w..16w+15 = tiles {w, w+8, w+16} (r,z,n aligned)
// + fc tile w. Per wave: 3 gh + 1 fc tiles (64 weight VGPRs, was 128),
// 4 gate-triples/thread (was 8) -> per-wave VALU/step halves, combined
// VGPR+AGPR ~125-135 (was ~180, 2-waves/SIMD limited). Same total work,
// 2x waves. Step structure, barriers, xi layout verbatim R10.
__global__ __launch_bounds__(512)
void gru_chunk(const short* __restrict__ xi_l, const int* __restrict__ done,
               const float* __restrict__ h0,
               const float* __restrict__ bhh, const float* __restrict__ fcb,
               const short* __restrict__ wHh, const short* __restrict__ wFc,
               float* __restrict__ out, float* __restrict__ hlast) {
    __shared__ short hT[2][16 * 136];
    __shared__ int doneL[Tt * 16];
    __shared__ int rbL[16];
    const int tid = threadIdx.x, w = tid >> 6, ln = tid & 63;
    const int q = ln & 15, lg = ln >> 4;
    const int bg = blockIdx.x, ck = blockIdx.y;
    const int t_c = ck * CL, t_end = t_c + CL;
    const int c = 16 * w + q;          // this thread's gate/hidden column

    {   // stage done[b][0..t_end) -> doneL[t][b]
        const int b = tid >> 5, i = tid & 31;
        const int* dp = done + (size_t)(bg * 16 + b) * Tt;
        for (int t = i; t < t_end; t += 32) doneL[t * 16 + b] = dp[t];
    }
    __syncthreads();
    if (tid < 16) {   // last reset before t_c
        int r = 0;
        for (int t = t_c - 1; t >= 0; --t)
            if (doneL[t * 16 + tid]) { r = t + 1; break; }
        rbL[tid] = r;
    }
    __syncthreads();
    int rmin = rbL[0];
#pragma unroll
    for (int b = 1; b < 16; b++) rmin = min(rmin, rbL[b]);

    // per-wave weights: gh tiles {w, w+8, w+16} (i=0:r, 1:z, 2:n), fc tile w
    short8 whh[3][4], wfc[4];
#pragma unroll
    for (int i = 0; i < 3; i++)
#pragma unroll
        for (int kf = 0; kf < 4; kf++)
            whh[i][kf] = *(const short8*)&wHh[(((w + 8 * i) * 4 + kf) * 64 + ln) * 8];
#pragma unroll
    for (int kf = 0; kf < 4; kf++)
        wfc[kf] = *(const short8*)&wFc[((w * 4 + kf) * 64 + ln) * 8];
    const float cbn = bhh[256 + c];
    const float cbf = fcb[c];

    float h_reg[4];
#pragma unroll
    for (int r = 0; r < 4; r++) {
        int bb = 4 * lg + r;
        h_reg[r] = (rbL[bb] == 0) ? h0[(size_t)(bg * 16 + bb) * Hd + c] : 0.f;
    }
    if (tid < 256) {   // hT[rmin&1] <- h_init (h0 if r_b==0 else 0)
        int row = tid >> 4, c0 = (tid & 15) * 8;
        short8 s0 = {0,0,0,0,0,0,0,0};
        if (rbL[row] == 0) {
            const float* hp = &h0[(size_t)(bg * 16 + row) * Hd + c0];
            f32x4 u0 = *(const f32x4*)&hp[0], u1 = *(const f32x4*)&hp[4];
#pragma unroll
            for (int i = 0; i < 4; i++) { s0[i] = f2bf(u0[i]); s0[i+4] = f2bf(u1[i]); }
        }
        *(short8*)&hT[rmin & 1][row * 136 + c0] = s0;
    }
    __syncthreads();

    // xi: tile nt at uint2-offset nt*64 within a t-frame of 1536; tiles w+8i
    const uint2* xp = (const uint2*)xi_l + ((size_t)bg * Tt + rmin) * 1536 + w * 64 + ln;
    uint2 cur[3];
#pragma unroll
    for (int i = 0; i < 3; i++) cur[i] = xp[i * 512];
    xp += 1536;

#pragma unroll 1
    for (int t = rmin; t < t_end; ++t) {
        const short* hTp = &hT[t & 1][0];
        short* hTn = &hT[(t + 1) & 1][0];
        short8 haf[4];
#pragma unroll
        for (int kf = 0; kf < 4; kf++)
            haf[kf] = *(const short8*)&hTp[q * 136 + kf * 32 + 8 * lg];

        // consume cur(t) -> acc init + xn8; issue loads for t+1 (older than
        // this iter's stores in vmcnt order)
        f32x4 acc[3];
        { f32x4 a = {bflo(cur[0].x), bfhi(cur[0].x), bflo(cur[0].y), bfhi(cur[0].y)}; acc[0] = a; }
        { f32x4 a = {bflo(cur[1].x), bfhi(cur[1].x), bflo(cur[1].y), bfhi(cur[1].y)}; acc[1] = a; }
        { f32x4 a = {cbn, cbn, cbn, cbn}; acc[2] = a; }
        uint2 xn8 = cur[2];
        if (t + 1 < t_end) {
#pragma unroll
            for (int i = 0; i < 3; i++) cur[i] = xp[i * 512];
        }
        xp += 1536;

        if (t > t_c) {   // FC+ELU+stores for frame t-1 (un-reset haf)
            f32x4 fca = {cbf, cbf, cbf, cbf};
#pragma unroll
            for (int kf = 0; kf < 4; kf++)
                fca = __builtin_amdgcn_mfma_f32_16x16x32_bf16(haf[kf], wfc[kf], fca, 0, 0, 0);
#pragma unroll
            for (int r = 0; r < 4; r++) {
                int bb = 4 * lg + r;
                float v = fca[r];
                float e = __expf(v) - 1.f;
                v = v > 0.f ? v : e;
                out[(((size_t)(bg * 16 + bb)) * Tt + (t - 1)) * Hd + c] = v;
            }
        }

        if (t > 0) {   // reset haf in place (FC above used un-reset value)
            int dn = doneL[(t - 1) * 16 + q];
            short8 z8 = {0,0,0,0,0,0,0,0};
#pragma unroll
            for (int kf = 0; kf < 4; kf++) haf[kf] = dn ? z8 : haf[kf];
        }
#pragma unroll
        for (int kf = 0; kf < 4; kf++) {
            acc[0] = __builtin_amdgcn_mfma_f32_16x16x32_bf16(haf[kf], whh[0][kf], acc[0], 0, 0, 0);
            acc[1] = __builtin_amdgcn_mfma_f32_16x16x32_bf16(haf[kf], whh[1][kf], acc[1], 0, 0, 0);
            acc[2] = __builtin_amdgcn_mfma_f32_16x16x32_bf16(haf[kf], whh[2][kf], acc[2], 0, 0, 0);
        }

        float rstf[4] = {1.f, 1.f, 1.f, 1.f};
        if (t > 0) {
            int4 dd = *(const int4*)&doneL[(t - 1) * 16 + 4 * lg];
            rstf[0] = dd.x ? 0.f : 1.f; rstf[1] = dd.y ? 0.f : 1.f;
            rstf[2] = dd.z ? 0.f : 1.f; rstf[3] = dd.w ? 0.f : 1.f;
        }
#pragma unroll
        for (int r = 0; r < 4; r++) {
            float rg = __builtin_amdgcn_rcpf(1.f + __expf(-acc[0][r]));
            float zg = __builtin_amdgcn_rcpf(1.f + __expf(-acc[1][r]));
            float xn = (r == 0) ? bflo(xn8.x) : (r == 1) ? bfhi(xn8.x)
                     : (r == 2) ? bflo(xn8.y) : bfhi(xn8.y);
            float aa = fmaf(rg, acc[2][r], xn);
            float ng = 1.f - 2.f * __builtin_amdgcn_rcpf(__expf(2.f * aa) + 1.f);
            float hp = h_reg[r] * rstf[r];
            float hn = (1.f - zg) * ng + zg * hp;
            h_reg[r] = hn;                       // un-reset
            hTn[(4 * lg + r) * 136 + c] = f2bf(hn);
        }
        // raw barrier: lgkmcnt(0) only, semantic intrinsic (no memory clobber)
        __builtin_amdgcn_sched_barrier(0);
        __builtin_amdgcn_s_waitcnt(0xC07F);
        __builtin_amdgcn_s_barrier();
        __builtin_amdgcn_sched_barrier(0);
    }
    {   // epilogue FC for frame t_end-1 (slot t_end&1 holds h_{t_end-1})
        const short* hTp = &hT[t_end & 1][0];
        short8 haf[4];
#pragma unroll
        for (int kf = 0; kf < 4; kf++)
            haf[kf] = *(const short8*)&hTp[q * 136 + kf * 32 + 8 * lg];
        f32x4 fca = {cbf, cbf, cbf, cbf};
#pragma unroll
        for (int kf = 0; kf < 4; kf++)
            fca = __builtin_amdgcn_mfma_f32_16x16x32_bf16(haf[kf], wfc[kf], fca, 0, 0, 0);
#pragma unroll
        for (int r = 0; r < 4; r++) {
            int bb = 4 * lg + r;
            float v = fca[r];
            float e = __expf(v) - 1.f;
            v = v > 0.f ? v : e;
            out[(((size_t)(bg * 16 + bb)) * Tt + (t_end - 1)) * Hd + c] = v;
        }
    }
    if (ck == NCK - 1) {   // h after step 255, un-reset
#pragma unroll
        for (int r = 0; r < 4; r++) {
            int bb = 4 * lg + r;
            hlast[(size_t)(bg * 16 + bb) * Hd + c] = h_reg[r];
        }
    }
}

extern "C" void kernel_launch(void* const* d_in, const int* in_sizes, int n_in,
                              void* d_out, int out_size, void* d_ws, size_t ws_size,
                              hipStream_t stream) {
    const float* x   = (const float*)d_in[0];
    const float* h0  = (const float*)d_in[1];
    const int*   dn  = (const int*)d_in[2];
    const float* Wih = (const float*)d_in[3];
    const float* Whh = (const float*)d_in[4];
    const float* bih = (const float*)d_in[5];
    const float* bhh = (const float*)d_in[6];
    const float* fcW = (const float*)d_in[7];
    const float* fcb = (const float*)d_in[8];

    short* wIh = (short*)d_ws;                 // 96 KB
    short* wHh = wIh + 49152;                  // 96 KB
    short* wFc = wHh + 49152;                  // 32 KB
    short* xi_l = wFc + 16384;                 // full-T xi: 201 MB
    float* out = (float*)d_out;
    float* hlast = out + (size_t)Bb * Tt * Hd;

    prep_weights<<<56, 256, 0, stream>>>(Wih, Whh, fcW, wIh, wHh, wFc);
    xi_gemm<<<dim3(64, Tt / 4), 512, 0, stream>>>(x, bih, bhh, wIh, xi_l);
    gru_chunk<<<dim3(64, NCK), 512, 0, stream>>>(xi_l, dn, h0, bhh, fcb,
                                                 wHh, wFc, out, hlast);
}

// Round 12
// 164.796 us; speedup vs baseline: 1.2014x; 1.2014x over previous
//
#include <hip/hip_runtime.h>
#include <hip/hip_bf16.h>
#include <math.h>

#define Hd 128
#define Tt 256
#define Bb 1024
#define CL 32           // time-chunk length (R12: 16->32, halves serial depth/CU)
#define NCK (Tt / CL)   // 8 chunks

typedef __attribute__((ext_vector_type(8))) short short8;
typedef __attribute__((ext_vector_type(4))) float f32x4;

__device__ __forceinline__ short f2bf(float f) {
    unsigned u = __float_as_uint(f);
    u += 0x7fffu + ((u >> 16) & 1u);   // RNE
    return (short)(u >> 16);
}
__device__ __forceinline__ float bflo(unsigned u) { return __uint_as_float(u << 16); }
__device__ __forceinline__ float bfhi(unsigned u) { return __uint_as_float(u & 0xffff0000u); }

// Weights -> bf16 MFMA B-frag layout [nt][kf][lane][8].  (verbatim)
__global__ void prep_weights(const float* __restrict__ Wih,
                             const float* __restrict__ Whh,
                             const float* __restrict__ fcW,
                             short* __restrict__ oIh, short* __restrict__ oHh,
                             short* __restrict__ oFc) {
    int t = blockIdx.x * 256 + threadIdx.x;
    if (t >= 14336) return;
    const float* src;
    short* dst;
    if (t < 6144)       { src = Wih; dst = oIh + t * 8; }
    else if (t < 12288) { t -= 6144;  src = Whh; dst = oHh + t * 8; }
    else                { t -= 12288; src = fcW; dst = oFc + t * 8; }
    int lane = t & 63, kf = (t >> 6) & 3, nt = t >> 8;
    const float* s = src + (nt * 16 + (lane & 15)) * 128 + kf * 32 + 8 * (lane >> 4);
#pragma unroll
    for (int j = 0; j < 8; j++) dst[j] = f2bf(s[j]);
}

// K2: xi = x@W_ih^T (+bih, +bhh for r/z cols) in C-frag order.  (verbatim)
__global__ __launch_bounds__(512)
void xi_gemm(const float* __restrict__ x, const float* __restrict__ bih,
             const float* __restrict__ bhh, const short* __restrict__ wIh,
             short* __restrict__ xi_l) {
    __shared__ short xs[64 * 136];
    const int tid = threadIdx.x, wv = tid >> 6, ln = tid & 63;
    const int q = ln & 15, lg = ln >> 4;
    const int bg = blockIdx.x;
    const int sl0 = blockIdx.y * 4;
    {
        const int row = tid >> 3, kq = tid & 7;
        const int b = row & 15, dt = row >> 4;
        const float* xp = x + (((size_t)(bg * 16 + b)) * Tt + (sl0 + dt)) * Hd + kq * 16;
        f32x4 u0 = *(const f32x4*)&xp[0],  u1 = *(const f32x4*)&xp[4];
        f32x4 u2 = *(const f32x4*)&xp[8],  u3 = *(const f32x4*)&xp[12];
        short8 s0, s1;
#pragma unroll
        for (int i = 0; i < 4; i++) { s0[i] = f2bf(u0[i]); s0[i+4] = f2bf(u1[i]);
                                      s1[i] = f2bf(u2[i]); s1[i+4] = f2bf(u3[i]); }
        *(short8*)&xs[row * 136 + kq * 16] = s0;
        *(short8*)&xs[row * 136 + kq * 16 + 8] = s1;
    }
    __syncthreads();
    short8 wb[3][4];
#pragma unroll
    for (int i = 0; i < 3; i++)
#pragma unroll
        for (int kf = 0; kf < 4; kf++)
            wb[i][kf] = *(const short8*)&wIh[(((wv + 8 * i) * 4 + kf) * 64 + ln) * 8];
    float biasv[3];
#pragma unroll
    for (int i = 0; i < 3; i++) {
        int c = (wv + 8 * i) * 16 + q;
        biasv[i] = bih[c] + (c < 256 ? bhh[c] : 0.f);
    }
#pragma unroll 1
    for (int mt = 0; mt < 4; mt++) {
        short8 af[4];
#pragma unroll
        for (int kf = 0; kf < 4; kf++)
            af[kf] = *(const short8*)&xs[(mt * 16 + q) * 136 + kf * 32 + 8 * lg];
        f32x4 c0 = {0,0,0,0}, c1 = {0,0,0,0}, c2 = {0,0,0,0};
#pragma unroll
        for (int kf = 0; kf < 4; kf++) {
            c0 = __builtin_amdgcn_mfma_f32_16x16x32_bf16(af[kf], wb[0][kf], c0, 0, 0, 0);
            c1 = __builtin_amdgcn_mfma_f32_16x16x32_bf16(af[kf], wb[1][kf], c1, 0, 0, 0);
            c2 = __builtin_amdgcn_mfma_f32_16x16x32_bf16(af[kf], wb[2][kf], c2, 0, 0, 0);
        }
#pragma unroll
        for (int i = 0; i < 3; i++) {
            f32x4 cc = (i == 0) ? c0 : (i == 1) ? c1 : c2;
            unsigned d0 = (unsigned)(unsigned short)f2bf(cc[0] + biasv[i]) |
                          ((unsigned)(unsigned short)f2bf(cc[1] + biasv[i]) << 16);
            unsigned d1 = (unsigned)(unsigned short)f2bf(cc[2] + biasv[i]) |
                          ((unsigned)(unsigned short)f2bf(cc[3] + biasv[i]) << 16);
            uint2 dd = {d0, d1};
            ((uint2*)xi_l)[(((size_t)bg * Tt + (sl0 + mt)) * 24 + (wv + 8 * i)) * 64 + ln] = dd;
        }
    }
}

// K3: time-chunked recurrence. R12 = R10 structure (4 waves, 256 thr, depth-1
// prefetch, semantic lgkm-only barrier) with CL=32: 512 blocks = exactly 2/CU
// co-resident in ONE round (R10: 4/CU in 2 rounds -> 46 serial block-steps;
// now ~38, -17%), prologue amortized 2x. Plus s_setprio(1) around the
// gh-MFMA->gates critical region (T5: 2 independent blocks/CU = role-diverse).
__global__ __launch_bounds__(256)
void gru_chunk(const short* __restrict__ xi_l, const int* __restrict__ done,
               const float* __restrict__ h0,
               const float* __restrict__ bhh, const float* __restrict__ fcb,
               const short* __restrict__ wHh, const short* __restrict__ wFc,
               float* __restrict__ out, float* __restrict__ hlast) {
    __shared__ short hT[2][16 * 136];
    __shared__ int doneL[Tt * 16];
    __shared__ int rbL[16];
    const int tid = threadIdx.x, j = tid >> 6, ln = tid & 63;
    const int q = ln & 15, lg = ln >> 4;
    const int bg = blockIdx.x, ck = blockIdx.y;
    const int t_c = ck * CL, t_end = t_c + CL;

    {   // stage done[b][0..t_end) -> doneL[t][b]
        const int b = tid >> 4, i = tid & 15;
        const int* dp = done + (size_t)(bg * 16 + b) * Tt;
        for (int t = i; t < t_end; t += 16) doneL[t * 16 + b] = dp[t];
    }
    __syncthreads();
    if (tid < 16) {   // last reset before t_c
        int r = 0;
        for (int t = t_c - 1; t >= 0; --t)
            if (doneL[t * 16 + tid]) { r = t + 1; break; }
        rbL[tid] = r;
    }
    __syncthreads();
    int rmin = rbL[0];
#pragma unroll
    for (int b = 1; b < 16; b++) rmin = min(rmin, rbL[b]);

    short8 whh[6][4], wfc[2][4];
#pragma unroll
    for (int i = 0; i < 6; i++)
#pragma unroll
        for (int kf = 0; kf < 4; kf++)
            whh[i][kf] = *(const short8*)&wHh[(((j + 4 * i) * 4 + kf) * 64 + ln) * 8];
#pragma unroll
    for (int cs = 0; cs < 2; cs++)
#pragma unroll
        for (int kf = 0; kf < 4; kf++)
            wfc[cs][kf] = *(const short8*)&wFc[(((j + 4 * cs) * 4 + kf) * 64 + ln) * 8];
    float cbn[2], cbf[2];
#pragma unroll
    for (int cs = 0; cs < 2; cs++) {
        int c = 16 * j + 64 * cs + q;
        cbn[cs] = bhh[256 + c];
        cbf[cs] = fcb[c];
    }

    float h_reg[2][4];
#pragma unroll
    for (int cs = 0; cs < 2; cs++)
#pragma unroll
        for (int r = 0; r < 4; r++) {
            int bb = 4 * lg + r, c = 16 * j + 64 * cs + q;
            h_reg[cs][r] = (rbL[bb] == 0) ? h0[(size_t)(bg * 16 + bb) * Hd + c] : 0.f;
        }
    {   // hT[rmin&1] <- h_init (h0 if r_b==0 else 0)
        int row = tid >> 4, c0 = (tid & 15) * 8;
        short8 s0 = {0,0,0,0,0,0,0,0};
        if (rbL[row] == 0) {
            const float* hp = &h0[(size_t)(bg * 16 + row) * Hd + c0];
            f32x4 u0 = *(const f32x4*)&hp[0], u1 = *(const f32x4*)&hp[4];
#pragma unroll
            for (int i = 0; i < 4; i++) { s0[i] = f2bf(u0[i]); s0[i+4] = f2bf(u1[i]); }
        }
        *(short8*)&hT[rmin & 1][row * 136 + c0] = s0;
    }
    __syncthreads();

    // xi pointer: tile (j+4i) at xp + i*256 (uint2), one t = +1536 (R6 layout)
    const uint2* xp = (const uint2*)xi_l + ((size_t)bg * Tt + rmin) * 1536 + j * 64 + ln;
    uint2 cur[6];
#pragma unroll
    for (int i = 0; i < 6; i++) cur[i] = xp[i * 256];
    xp += 1536;

#pragma unroll 1
    for (int t = rmin; t < t_end; ++t) {
        const short* hTp = &hT[t & 1][0];
        short* hTn = &hT[(t + 1) & 1][0];
        short8 haf[4];
#pragma unroll
        for (int kf = 0; kf < 4; kf++)
            haf[kf] = *(const short8*)&hTp[q * 136 + kf * 32 + 8 * lg];

        // consume cur(t) -> acc init + xn8, then ISSUE loads for t+1 (older
        // than this iter's stores in vmcnt order)
        f32x4 acc[6];
#pragma unroll
        for (int i = 0; i < 4; i++) {
            f32x4 a = {bflo(cur[i].x), bfhi(cur[i].x), bflo(cur[i].y), bfhi(cur[i].y)};
            acc[i] = a;
        }
        { f32x4 a = {cbn[0], cbn[0], cbn[0], cbn[0]}; acc[4] = a; }
        { f32x4 a = {cbn[1], cbn[1], cbn[1], cbn[1]}; acc[5] = a; }
        uint2 xn8[2] = {cur[4], cur[5]};
        if (t + 1 < t_end) {
#pragma unroll
            for (int i = 0; i < 6; i++) cur[i] = xp[i * 256];
        }
        xp += 1536;

        if (t > t_c) {   // FC+ELU+stores for frame t-1 (un-reset haf)
            f32x4 fca[2];
            { f32x4 a = {cbf[0], cbf[0], cbf[0], cbf[0]}; fca[0] = a; }
            { f32x4 a = {cbf[1], cbf[1], cbf[1], cbf[1]}; fca[1] = a; }
#pragma unroll
            for (int kf = 0; kf < 4; kf++)
#pragma unroll
                for (int cs = 0; cs < 2; cs++)
                    fca[cs] = __builtin_amdgcn_mfma_f32_16x16x32_bf16(haf[kf], wfc[cs][kf], fca[cs], 0, 0, 0);
#pragma unroll
            for (int cs = 0; cs < 2; cs++)
#pragma unroll
                for (int r = 0; r < 4; r++) {
                    int bb = 4 * lg + r, c = 16 * j + 64 * cs + q;
                    float v = fca[cs][r];
                    float e = __expf(v) - 1.f;
                    v = v > 0.f ? v : e;
                    out[(((size_t)(bg * 16 + bb)) * Tt + (t - 1)) * Hd + c] = v;
                }
        }

        if (t > 0) {   // reset haf in place (FC above used un-reset value)
            int dn = doneL[(t - 1) * 16 + q];
            short8 z8 = {0,0,0,0,0,0,0,0};
#pragma unroll
            for (int kf = 0; kf < 4; kf++) haf[kf] = dn ? z8 : haf[kf];
        }
        __builtin_amdgcn_s_setprio(1);   // T5: favor the h-critical region
#pragma unroll
        for (int kf = 0; kf < 4; kf++)
#pragma unroll
            for (int i = 0; i < 6; i++)
                acc[i] = __builtin_amdgcn_mfma_f32_16x16x32_bf16(haf[kf], whh[i][kf], acc[i], 0, 0, 0);

        float rstf[4] = {1.f, 1.f, 1.f, 1.f};
        if (t > 0) {
            int4 dd = *(const int4*)&doneL[(t - 1) * 16 + 4 * lg];
            rstf[0] = dd.x ? 0.f : 1.f; rstf[1] = dd.y ? 0.f : 1.f;
            rstf[2] = dd.z ? 0.f : 1.f; rstf[3] = dd.w ? 0.f : 1.f;
        }
#pragma unroll
        for (int cs = 0; cs < 2; cs++) {
#pragma unroll
            for (int r = 0; r < 4; r++) {
                float rg = __builtin_amdgcn_rcpf(1.f + __expf(-acc[cs][r]));
                float zg = __builtin_amdgcn_rcpf(1.f + __expf(-acc[2 + cs][r]));
                float xn = (r == 0) ? bflo(xn8[cs].x) : (r == 1) ? bfhi(xn8[cs].x)
                         : (r == 2) ? bflo(xn8[cs].y) : bfhi(xn8[cs].y);
                float aa = fmaf(rg, acc[4 + cs][r], xn);
                float ng = 1.f - 2.f * __builtin_amdgcn_rcpf(__expf(2.f * aa) + 1.f);
                float hp = h_reg[cs][r] * rstf[r];
                float hn = (1.f - zg) * ng + zg * hp;
                h_reg[cs][r] = hn;                       // un-reset
                hTn[(4 * lg + r) * 136 + 16 * j + 64 * cs + q] = f2bf(hn);
            }
        }
        __builtin_amdgcn_s_setprio(0);
        // raw barrier: lgkmcnt(0) only, semantic intrinsic (no memory clobber)
        __builtin_amdgcn_sched_barrier(0);
        __builtin_amdgcn_s_waitcnt(0xC07F);
        __builtin_amdgcn_s_barrier();
        __builtin_amdgcn_sched_barrier(0);
    }
    {   // epilogue FC for frame t_end-1 (slot t_end&1 holds h_{t_end-1})
        const short* hTp = &hT[t_end & 1][0];
        short8 haf[4];
#pragma unroll
        for (int kf = 0; kf < 4; kf++)
            haf[kf] = *(const short8*)&hTp[q * 136 + kf * 32 + 8 * lg];
        f32x4 fca[2];
        { f32x4 a = {cbf[0], cbf[0], cbf[0], cbf[0]}; fca[0] = a; }
        { f32x4 a = {cbf[1], cbf[1], cbf[1], cbf[1]}; fca[1] = a; }
#pragma unroll
        for (int kf = 0; kf < 4; kf++)
#pragma unroll
            for (int cs = 0; cs < 2; cs++)
                fca[cs] = __builtin_amdgcn_mfma_f32_16x16x32_bf16(haf[kf], wfc[cs][kf], fca[cs], 0, 0, 0);
#pragma unroll
        for (int cs = 0; cs < 2; cs++)
#pragma unroll
            for (int r = 0; r < 4; r++) {
                int bb = 4 * lg + r, c = 16 * j + 64 * cs + q;
                float v = fca[cs][r];
                float e = __expf(v) - 1.f;
                v = v > 0.f ? v : e;
                out[(((size_t)(bg * 16 + bb)) * Tt + (t_end - 1)) * Hd + c] = v;
            }
    }
    if (ck == NCK - 1) {   // h after step 255, un-reset
#pragma unroll
        for (int cs = 0; cs < 2; cs++)
#pragma unroll
            for (int r = 0; r < 4; r++) {
                int bb = 4 * lg + r, c = 16 * j + 64 * cs + q;
                hlast[(size_t)(bg * 16 + bb) * Hd + c] = h_reg[cs][r];
            }
    }
}

extern "C" void kernel_launch(void* const* d_in, const int* in_sizes, int n_in,
                              void* d_out, int out_size, void* d_ws, size_t ws_size,
                              hipStream_t stream) {
    const float* x   = (const float*)d_in[0];
    const float* h0  = (const float*)d_in[1];
    const int*   dn  = (const int*)d_in[2];
    const float* Wih = (const float*)d_in[3];
    const float* Whh = (const float*)d_in[4];
    const float* bih = (const float*)d_in[5];
    const float* bhh = (const float*)d_in[6];
    const float* fcW = (const float*)d_in[7];
    const float* fcb = (const float*)d_in[8];

    short* wIh = (short*)d_ws;                 // 96 KB
    short* wHh = wIh + 49152;                  // 96 KB
    short* wFc = wHh + 49152;                  // 32 KB
    short* xi_l = wFc + 16384;                 // full-T xi: 201 MB
    float* out = (float*)d_out;
    float* hlast = out + (size_t)Bb * Tt * Hd;

    prep_weights<<<56, 256, 0, stream>>>(Wih, Whh, fcW, wIh, wHh, wFc);
    xi_gemm<<<dim3(64, Tt / 4), 512, 0, stream>>>(x, bih, bhh, wIh, xi_l);
    gru_chunk<<<dim3(64, NCK), 256, 0, stream>>>(xi_l, dn, h0, bhh, fcb,
                                                 wHh, wFc, out, hlast);
}